// Round 1
// 501.056 us; speedup vs baseline: 1.0287x; 1.0287x over previous
//
#include <hip/hip_runtime.h>

#define N_NODES 50000
#define N_EDGES 1600000
#define IN_DIM 512
#define OUT_DIM 256

#define BM 128
#define BN 128
#define BK 32
#define APAD 8                 // pad rows to 40 shorts = 80 B -> 2-way banks (free)
#define LDA (BK + APAD)

typedef unsigned int u32;
typedef unsigned short u16;
typedef short bf16x8 __attribute__((ext_vector_type(8)));
typedef float f32x4 __attribute__((ext_vector_type(4)));

__device__ __forceinline__ float bf_to_f(u16 u) { return __uint_as_float(((u32)u) << 16); }
__device__ __forceinline__ u16 f_to_bf(float f) {
    u32 u = __float_as_uint(f);
    u32 r = (u + 0x7fffu + ((u >> 16) & 1u)) >> 16;   // RNE
    return (u16)r;
}

// ---------------------------------------------------------------------------
// CSR build
// ---------------------------------------------------------------------------
__global__ __launch_bounds__(256) void zero_cnt(int* __restrict__ cnt) {
    const int i = blockIdx.x * blockDim.x + threadIdx.x;
    if (i < N_NODES) cnt[i] = 0;
}

__global__ __launch_bounds__(256) void hist(const int* __restrict__ er,
                                            int* __restrict__ cnt) {
    const int e = blockIdx.x * blockDim.x + threadIdx.x;
    if (e < N_EDGES) atomicAdd(&cnt[er[e]], 1);
}

// pass 1: per-block (256-wide) exclusive scan; block totals to bsum
__global__ __launch_bounds__(256) void scan1(const int* __restrict__ cnt,
                                             int* __restrict__ row_ptr,
                                             int* __restrict__ bsum) {
    __shared__ int sh[256];
    const int t = threadIdx.x;
    const int i = blockIdx.x * 256 + t;
    const int v = (i < N_NODES) ? cnt[i] : 0;
    sh[t] = v;
    __syncthreads();
    #pragma unroll
    for (int off = 1; off < 256; off <<= 1) {
        const int tv = (t >= off) ? sh[t - off] : 0;
        __syncthreads();
        sh[t] += tv;
        __syncthreads();
    }
    if (i < N_NODES) row_ptr[i] = sh[t] - v;          // block-local exclusive
    if (t == 255) bsum[blockIdx.x] = sh[255];
}

// pass 2: scan the 196 block sums (single block)
__global__ __launch_bounds__(256) void scan2(int* __restrict__ bsum, int nb) {
    __shared__ int sh[256];
    const int t = threadIdx.x;
    const int v = (t < nb) ? bsum[t] : 0;
    sh[t] = v;
    __syncthreads();
    #pragma unroll
    for (int off = 1; off < 256; off <<= 1) {
        const int tv = (t >= off) ? sh[t - off] : 0;
        __syncthreads();
        sh[t] += tv;
        __syncthreads();
    }
    if (t < nb) bsum[t] = sh[t] - v;                  // exclusive block prefix
}

// pass 3: add block prefix; produce row_ptr + cursor
__global__ __launch_bounds__(256) void scan3(int* __restrict__ row_ptr,
                                             const int* __restrict__ bsum,
                                             int* __restrict__ cursor) {
    const int t = threadIdx.x;
    const int i = blockIdx.x * 256 + t;
    if (i < N_NODES) {
        const int r = row_ptr[i] + bsum[blockIdx.x];
        row_ptr[i] = r;
        cursor[i]  = r;
    }
    if (blockIdx.x == 0 && t == 0) row_ptr[N_NODES] = N_EDGES;
}

// bucket edges into row-sorted order; (col, valbits) packed as int2
__global__ __launch_bounds__(256) void bucket(const int* __restrict__ er,
                                              const int* __restrict__ ec,
                                              const float* __restrict__ ev,
                                              int* __restrict__ cursor,
                                              int2* __restrict__ sedge) {
    const int e = blockIdx.x * blockDim.x + threadIdx.x;
    if (e >= N_EDGES) return;
    const int r = er[e];
    const int pos = atomicAdd(&cursor[r], 1);
    sedge[pos] = make_int2(ec[e], __float_as_int(ev[e]));
}

// ---------------------------------------------------------------------------
// W [512,256] fp32  ->  WT [256,512] bf16 (transposed, K-contiguous)
// block handles 4 k-rows x 256 n; reads coalesced, writes ushort4
// ---------------------------------------------------------------------------
__global__ __launch_bounds__(256) void wcvt(const float* __restrict__ W,
                                            u16* __restrict__ WT) {
    const int n  = threadIdx.x;
    const int k0 = blockIdx.x * 4;
    ushort4 o;
    o.x = f_to_bf(W[(size_t)(k0 + 0) * OUT_DIM + n]);
    o.y = f_to_bf(W[(size_t)(k0 + 1) * OUT_DIM + n]);
    o.z = f_to_bf(W[(size_t)(k0 + 2) * OUT_DIM + n]);
    o.w = f_to_bf(W[(size_t)(k0 + 3) * OUT_DIM + n]);
    *(ushort4*)(WT + (size_t)n * IN_DIM + k0) = o;
}

// ---------------------------------------------------------------------------
// GEMM: Sb[M,256] = bf16( X[M,512] @ W[512,256] ), MFMA 16x16x32 bf16
// block = 256 thr = 4 waves; tile 128x128; wave computes 64x64 (4x4 tiles)
// A-staging converts fp32 X -> bf16 LDS on the fly; B comes from WT (bf16)
// ---------------------------------------------------------------------------
__global__ __launch_bounds__(256) void gemm_mfma(const float* __restrict__ X,
                                                 const u16* __restrict__ WT,
                                                 u16* __restrict__ Sb) {
    __shared__ u16 As[BM * LDA];   // [m][k] k-contiguous, 10 KB
    __shared__ u16 Bs[BN * LDA];   // [n][k] k-contiguous, 10 KB

    const int tid  = threadIdx.x;
    const int wave = tid >> 6;
    const int lane = tid & 63;
    const int r0   = blockIdx.x * BM;
    const int n0   = blockIdx.y * BN;
    const int wm   = (wave & 1) * 64;
    const int wn   = (wave >> 1) * 64;
    const int l15  = lane & 15;
    const int quad = lane >> 4;

    f32x4 acc[4][4];
    #pragma unroll
    for (int i = 0; i < 4; ++i)
        #pragma unroll
        for (int j = 0; j < 4; ++j) acc[i][j] = (f32x4)0.f;

    // staging coords: thread -> (row = tid>>1, kpart = (tid&1)*16)
    const int srow = tid >> 1;
    const int skp  = (tid & 1) * 16;
    // clamp X row so the last block never reads OOB (stores are masked)
    const int xrow = min(r0 + srow, N_NODES - 1);
    const float* xsrc = X + (size_t)xrow * IN_DIM + skp;
    const u16*   bsrc = WT + (size_t)(n0 + srow) * IN_DIM + skp;

    for (int kc = 0; kc < IN_DIM; kc += BK) {
        // ---- stage A: 16 fp32 -> 16 bf16 per thread
        {
            const float4 f0 = *(const float4*)(xsrc + kc + 0);
            const float4 f1 = *(const float4*)(xsrc + kc + 4);
            const float4 f2 = *(const float4*)(xsrc + kc + 8);
            const float4 f3 = *(const float4*)(xsrc + kc + 12);
            ushort4 p0, p1, p2, p3;
            p0.x = f_to_bf(f0.x); p0.y = f_to_bf(f0.y); p0.z = f_to_bf(f0.z); p0.w = f_to_bf(f0.w);
            p1.x = f_to_bf(f1.x); p1.y = f_to_bf(f1.y); p1.z = f_to_bf(f1.z); p1.w = f_to_bf(f1.w);
            p2.x = f_to_bf(f2.x); p2.y = f_to_bf(f2.y); p2.z = f_to_bf(f2.z); p2.w = f_to_bf(f2.w);
            p3.x = f_to_bf(f3.x); p3.y = f_to_bf(f3.y); p3.z = f_to_bf(f3.z); p3.w = f_to_bf(f3.w);
            *(ushort4*)&As[srow * LDA + skp + 0]  = p0;
            *(ushort4*)&As[srow * LDA + skp + 4]  = p1;
            *(ushort4*)&As[srow * LDA + skp + 8]  = p2;
            *(ushort4*)&As[srow * LDA + skp + 12] = p3;
        }
        // ---- stage B: 16 bf16 per thread (already converted)
        {
            const uint4 b0 = *(const uint4*)(bsrc + kc);      // 8 bf16
            const uint4 b1 = *(const uint4*)(bsrc + kc + 8);  // 8 bf16
            *(uint4*)&Bs[srow * LDA + skp + 0] = b0;
            *(uint4*)&Bs[srow * LDA + skp + 8] = b1;
        }
        __syncthreads();

        bf16x8 af[4], bf[4];
        #pragma unroll
        for (int mt = 0; mt < 4; ++mt)
            af[mt] = *(const bf16x8*)&As[(wm + mt * 16 + l15) * LDA + quad * 8];
        #pragma unroll
        for (int nt = 0; nt < 4; ++nt)
            bf[nt] = *(const bf16x8*)&Bs[(wn + nt * 16 + l15) * LDA + quad * 8];
        #pragma unroll
        for (int mt = 0; mt < 4; ++mt)
            #pragma unroll
            for (int nt = 0; nt < 4; ++nt)
                acc[mt][nt] = __builtin_amdgcn_mfma_f32_16x16x32_bf16(
                    af[mt], bf[nt], acc[mt][nt], 0, 0, 0);
        __syncthreads();
    }

    // epilogue: D[row = quad*4 + r][col = l15] per 16x16 tile
    #pragma unroll
    for (int mt = 0; mt < 4; ++mt) {
        #pragma unroll
        for (int r = 0; r < 4; ++r) {
            const int grow = r0 + wm + mt * 16 + quad * 4 + r;
            if (grow < N_NODES) {
                u16* dst = Sb + (size_t)grow * OUT_DIM + n0 + wn + l15;
                #pragma unroll
                for (int nt = 0; nt < 4; ++nt)
                    dst[nt * 16] = f_to_bf(acc[mt][nt][r]);
            }
        }
    }
}

// ---------------------------------------------------------------------------
// out[r] = bias + sum_{e in row r} val[e] * Sb[col[e]]   (bf16 gather, fp32 acc)
// one wave per row; lane = 4 channels (256 ch = 64 lanes x ushort4 gather).
// Edge loop runs in predicated 8-wide batches: 8 independent wave-uniform
// edge loads + 8 independent row-gathers are all in flight before any FMA
// (degree ~ Poisson(32): the old 64-edge shfl path never executed; the
// un-unrolled remainder loop held ~1 outstanding gather -> latency-bound:
// MfmaUtil 0 / VALUBusy 26% / HBM 40%).
// Padding lanes re-load sedge[end-1] (L1 hit) with weight forced to 0.
// ---------------------------------------------------------------------------
__global__ __launch_bounds__(256) void csr_spmm(const int* __restrict__ row_ptr,
                                                const int2* __restrict__ sedge,
                                                const u16* __restrict__ Sb,
                                                const float* __restrict__ bias,
                                                float* __restrict__ out) {
    const int wave = threadIdx.x >> 6;
    const int lane = threadIdx.x & 63;
    const int r = blockIdx.x * 4 + wave;
    if (r >= N_NODES) return;

    const int start = row_ptr[r];
    const int end   = row_ptr[r + 1];

    float4 acc = *(const float4*)(bias + lane * 4);
    const u16* sbase = Sb + lane * 4;

    for (int e = start; e < end; e += 8) {
        // 1) issue 8 independent edge loads (wave-uniform addr -> broadcast)
        int2 ed[8];
        #pragma unroll
        for (int j = 0; j < 8; ++j) {
            const int idx = min(e + j, end - 1);      // clamp: safe, row nonempty here
            ed[j] = sedge[idx];
        }
        // zero the weight on padding slots (gather still issued, hits L1)
        #pragma unroll
        for (int j = 0; j < 8; ++j)
            if (e + j >= end) ed[j].y = 0;            // 0.0f bits

        // 2) issue 8 independent row gathers (8 B/lane, 512 B/wave each)
        ushort4 sv[8];
        #pragma unroll
        for (int j = 0; j < 8; ++j)
            sv[j] = *(const ushort4*)(sbase + (size_t)ed[j].x * OUT_DIM);

        // 3) accumulate
        #pragma unroll
        for (int j = 0; j < 8; ++j) {
            const float vj = __int_as_float(ed[j].y);
            acc.x += vj * bf_to_f(sv[j].x);
            acc.y += vj * bf_to_f(sv[j].y);
            acc.z += vj * bf_to_f(sv[j].z);
            acc.w += vj * bf_to_f(sv[j].w);
        }
    }

    *(float4*)(out + (size_t)r * OUT_DIM + lane * 4) = acc;
}

extern "C" void kernel_launch(void* const* d_in, const int* in_sizes, int n_in,
                              void* d_out, int out_size, void* d_ws, size_t ws_size,
                              hipStream_t stream) {
    const float* X    = (const float*)d_in[0];
    const int*   er   = (const int*)d_in[1];
    const int*   ec   = (const int*)d_in[2];
    const float* ev   = (const float*)d_in[3];
    const float* W    = (const float*)d_in[4];
    const float* bias = (const float*)d_in[5];
    float* out        = (float*)d_out;

    // ws layout (~39.3 MB total)
    char* ws = (char*)d_ws;
    u16*  Sb      = (u16*) (ws);                       // 25,600,000 B
    u16*  WT      = (u16*) (ws + 25600000);            //    262,144 B
    int2* sedge   = (int2*)(ws + 25862144);            // 12,800,000 B
    int*  cnt     = (int*) (ws + 38662144);            //    200,000 B
    int*  row_ptr = (int*) (ws + 38862144);            //    200,004 B
    int*  cursor  = (int*) (ws + 39062160);            //    200,000 B
    int*  bsum    = (int*) (ws + 39262160);            //        784 B

    const int nb = (N_NODES + 255) / 256;              // 196

    hipLaunchKernelGGL(zero_cnt, dim3(nb), dim3(256), 0, stream, cnt);
    hipLaunchKernelGGL(hist, dim3(N_EDGES / 256), dim3(256), 0, stream, er, cnt);
    hipLaunchKernelGGL(scan1, dim3(nb), dim3(256), 0, stream, cnt, row_ptr, bsum);
    hipLaunchKernelGGL(scan2, dim3(1), dim3(256), 0, stream, bsum, nb);
    hipLaunchKernelGGL(scan3, dim3(nb), dim3(256), 0, stream, row_ptr, bsum, cursor);
    hipLaunchKernelGGL(bucket, dim3(N_EDGES / 256), dim3(256), 0, stream,
                       er, ec, ev, cursor, sedge);
    hipLaunchKernelGGL(wcvt, dim3(IN_DIM / 4), dim3(256), 0, stream, W, WT);
    hipLaunchKernelGGL(gemm_mfma, dim3((N_NODES + BM - 1) / BM, OUT_DIM / BN),
                       dim3(256), 0, stream, X, WT, Sb);
    hipLaunchKernelGGL(csr_spmm, dim3((N_NODES + 3) / 4), dim3(256), 0, stream,
                       row_ptr, sedge, Sb, bias, out);
}

// Round 2
// 359.174 us; speedup vs baseline: 1.4350x; 1.3950x over previous
//
#include <hip/hip_runtime.h>

#define N_NODES 50000
#define N_EDGES 1600000
#define IN_DIM 512
#define OUT_DIM 256

#define BM 128
#define BN 128
#define BK 32
#define APAD 8                 // pad rows to 40 shorts = 80 B -> 2-way banks (free)
#define LDA (BK + APAD)

// ---- two-level counting sort geometry ----
#define RPB   128              // rows per bucket (rloc = 7 bits)
#define NBKT  391              // ceil(50000 / 128)
#define CHUNK 4096             // edges per scatter1 block
#define CAP   5120             // per-bucket tmp capacity (mean 4096, sigma 64 -> +16 sigma)

typedef unsigned int u32;
typedef unsigned short u16;
typedef short bf16x8 __attribute__((ext_vector_type(8)));
typedef float f32x4 __attribute__((ext_vector_type(4)));

__device__ __forceinline__ float bf_to_f(u16 u) { return __uint_as_float(((u32)u) << 16); }
__device__ __forceinline__ u16 f_to_bf(float f) {
    u32 u = __float_as_uint(f);
    u32 r = (u + 0x7fffu + ((u >> 16) & 1u)) >> 16;   // RNE
    return (u16)r;
}

// ---------------------------------------------------------------------------
// CSR build, two-level. Replaces hist + 3 scans + bucket (1.6M global atomics
// + 1.6M random 8B stores = 101MB line writes, both latency-bound at
// VALUBusy 0.4% / HBM 11%).  Level 1 bins edges into 391 row-buckets with
// LDS atomics + one global atomic per (block,bucket); level 2 sorts each
// bucket within a 32KB L2-resident window with LDS cursors.
// ---------------------------------------------------------------------------
__global__ __launch_bounds__(256) void zero_cur(int* __restrict__ cursor) {
    const int i = blockIdx.x * 256 + threadIdx.x;
    if (i < NBKT) cursor[i] = 0;
}

// edges -> bucket-major tmp (fixed CAP per bucket).  Edge packed as
// w0 = col | (rloc<<16) | (bkt<<23), w1 = val bits (col < 65536, rloc < 128).
__global__ __launch_bounds__(256) void scatter1(const int* __restrict__ er,
                                                const int* __restrict__ ec,
                                                const float* __restrict__ ev,
                                                int* __restrict__ cursor,
                                                int2* __restrict__ tmp) {
    __shared__ int  hcnt[NBKT];
    __shared__ int  loff[NBKT];
    __shared__ int  gbase[NBKT];
    __shared__ int  sc[512];
    __shared__ int2 estage[CHUNK];   // 32 KB
    __shared__ u16  bslot[CHUNK];    // 8 KB

    const int t = threadIdx.x;
    const int base = blockIdx.x * CHUNK;
    const int nedge = min(CHUNK, N_EDGES - base);

    for (int k = t; k < NBKT; k += 256) hcnt[k] = 0;
    __syncthreads();

    // count + per-edge rank via LDS atomic-return
    int w0[16], w1[16], rk[16];
    #pragma unroll
    for (int j = 0; j < 16; ++j) {
        const int i = j * 256 + t;            // coalesced per j
        rk[j] = -1;
        if (i < nedge) {
            const int e = base + i;
            const int r = er[e];
            const int bk = r >> 7;
            w0[j] = ec[e] | ((r & 127) << 16) | (bk << 23);
            w1[j] = __float_as_int(ev[e]);
            rk[j] = atomicAdd(&hcnt[bk], 1);
        }
    }
    __syncthreads();

    // exclusive scan of hcnt (padded to 512, Hillis-Steele, 2 elems/thread)
    sc[t]       = (t < NBKT) ? hcnt[t] : 0;
    sc[t + 256] = (t + 256 < NBKT) ? hcnt[t + 256] : 0;
    __syncthreads();
    #pragma unroll
    for (int off = 1; off < 512; off <<= 1) {
        const int a0 = (t >= off) ? sc[t - off] : 0;
        const int a1 = sc[t + 256 - off];
        __syncthreads();
        sc[t] += a0;
        sc[t + 256] += a1;
        __syncthreads();
    }
    if (t < NBKT)       loff[t]       = sc[t] - hcnt[t];
    if (t + 256 < NBKT) loff[t + 256] = sc[t + 256] - hcnt[t + 256];

    // reserve global space: ONE atomic per (block,bucket) instead of per edge
    if (t < NBKT && hcnt[t] > 0)
        gbase[t] = t * CAP + atomicAdd(&cursor[t], hcnt[t]);
    if (t + 256 < NBKT && hcnt[t + 256] > 0)
        gbase[t + 256] = (t + 256) * CAP + atomicAdd(&cursor[t + 256], hcnt[t + 256]);
    __syncthreads();

    // reorder bucket-major in LDS
    #pragma unroll
    for (int j = 0; j < 16; ++j) {
        if (rk[j] >= 0) {
            const int bk = ((u32)w0[j]) >> 23;
            const int s = loff[bk] + rk[j];
            estage[s] = make_int2(w0[j], w1[j]);
            bslot[s]  = (u16)bk;
        }
    }
    __syncthreads();

    // write out: consecutive slots -> consecutive global addrs per bucket run
    for (int s = t; s < nedge; s += 256) {
        const int bk = bslot[s];
        const int2 e2 = estage[s];
        const int gpos = gbase[bk] + (s - loff[bk]);
        if (gpos < (bk + 1) * CAP)            // overflow guard (never in practice)
            tmp[gpos] = e2;
    }
}

// scan 391 bucket counts -> bucket_base; set row_ptr sentinel
__global__ __launch_bounds__(256) void bscan(const int* __restrict__ cursor,
                                             int* __restrict__ bucket_base,
                                             int* __restrict__ row_ptr) {
    __shared__ int sc[512];
    __shared__ int orig[512];
    const int t = threadIdx.x;
    const int c0 = (t < NBKT) ? min(cursor[t], CAP) : 0;
    const int c1 = (t + 256 < NBKT) ? min(cursor[t + 256], CAP) : 0;
    sc[t] = c0;       orig[t] = c0;
    sc[t + 256] = c1; orig[t + 256] = c1;
    __syncthreads();
    #pragma unroll
    for (int off = 1; off < 512; off <<= 1) {
        const int a0 = (t >= off) ? sc[t - off] : 0;
        const int a1 = sc[t + 256 - off];
        __syncthreads();
        sc[t] += a0;
        sc[t + 256] += a1;
        __syncthreads();
    }
    if (t < NBKT)       bucket_base[t]       = sc[t] - orig[t];
    if (t + 256 < NBKT) bucket_base[t + 256] = sc[t + 256] - orig[t + 256];
    if (t == 0) row_ptr[N_NODES] = N_EDGES;
}

// per bucket: LDS row-hist + scan -> row_ptr; scatter into 32KB window
__global__ __launch_bounds__(256) void scatter2(const int* __restrict__ cursor,
                                                const int* __restrict__ bucket_base,
                                                const int2* __restrict__ tmp,
                                                int* __restrict__ row_ptr,
                                                int2* __restrict__ sedge) {
    __shared__ int rcnt[RPB];
    __shared__ int sc[RPB];
    __shared__ int rcur[RPB];
    const int t = threadIdx.x;
    const int b = blockIdx.x;
    const int n = min(cursor[b], CAP);
    const int2* src = tmp + (size_t)b * CAP;
    const int gb = bucket_base[b];

    if (t < RPB) rcnt[t] = 0;
    __syncthreads();
    for (int i = t; i < n; i += 256)
        atomicAdd(&rcnt[(((u32)src[i].x) >> 16) & 127], 1);
    __syncthreads();

    if (t < RPB) sc[t] = rcnt[t];
    __syncthreads();
    #pragma unroll
    for (int off = 1; off < RPB; off <<= 1) {
        int a = 0;
        if (t < RPB && t >= off) a = sc[t - off];
        __syncthreads();
        if (t < RPB) sc[t] += a;
        __syncthreads();
    }
    if (t < RPB) {
        const int excl = sc[t] - rcnt[t];
        rcur[t] = gb + excl;
        const int row = b * RPB + t;
        if (row < N_NODES) row_ptr[row] = gb + excl;
    }
    __syncthreads();

    for (int i = t; i < n; i += 256) {
        const int2 e2 = src[i];                       // L2-hot (2nd pass)
        const int rloc = (((u32)e2.x) >> 16) & 127;
        const int pos = atomicAdd(&rcur[rloc], 1);    // LDS atomic
        sedge[pos] = make_int2(e2.x & 0xFFFF, e2.y);  // within 32KB window
    }
}

// ---------------------------------------------------------------------------
// W [512,256] fp32  ->  WT [256,512] bf16 (transposed, K-contiguous)
// ---------------------------------------------------------------------------
__global__ __launch_bounds__(256) void wcvt(const float* __restrict__ W,
                                            u16* __restrict__ WT) {
    const int n  = threadIdx.x;
    const int k0 = blockIdx.x * 4;
    ushort4 o;
    o.x = f_to_bf(W[(size_t)(k0 + 0) * OUT_DIM + n]);
    o.y = f_to_bf(W[(size_t)(k0 + 1) * OUT_DIM + n]);
    o.z = f_to_bf(W[(size_t)(k0 + 2) * OUT_DIM + n]);
    o.w = f_to_bf(W[(size_t)(k0 + 3) * OUT_DIM + n]);
    *(ushort4*)(WT + (size_t)n * IN_DIM + k0) = o;
}

// ---------------------------------------------------------------------------
// GEMM: Sb[M,256] = bf16( X[M,512] @ W[512,256] ), MFMA 16x16x32 bf16
// ---------------------------------------------------------------------------
__global__ __launch_bounds__(256) void gemm_mfma(const float* __restrict__ X,
                                                 const u16* __restrict__ WT,
                                                 u16* __restrict__ Sb) {
    __shared__ u16 As[BM * LDA];
    __shared__ u16 Bs[BN * LDA];

    const int tid  = threadIdx.x;
    const int wave = tid >> 6;
    const int lane = tid & 63;
    const int r0   = blockIdx.x * BM;
    const int n0   = blockIdx.y * BN;
    const int wm   = (wave & 1) * 64;
    const int wn   = (wave >> 1) * 64;
    const int l15  = lane & 15;
    const int quad = lane >> 4;

    f32x4 acc[4][4];
    #pragma unroll
    for (int i = 0; i < 4; ++i)
        #pragma unroll
        for (int j = 0; j < 4; ++j) acc[i][j] = (f32x4)0.f;

    const int srow = tid >> 1;
    const int skp  = (tid & 1) * 16;
    const int xrow = min(r0 + srow, N_NODES - 1);
    const float* xsrc = X + (size_t)xrow * IN_DIM + skp;
    const u16*   bsrc = WT + (size_t)(n0 + srow) * IN_DIM + skp;

    for (int kc = 0; kc < IN_DIM; kc += BK) {
        {
            const float4 f0 = *(const float4*)(xsrc + kc + 0);
            const float4 f1 = *(const float4*)(xsrc + kc + 4);
            const float4 f2 = *(const float4*)(xsrc + kc + 8);
            const float4 f3 = *(const float4*)(xsrc + kc + 12);
            ushort4 p0, p1, p2, p3;
            p0.x = f_to_bf(f0.x); p0.y = f_to_bf(f0.y); p0.z = f_to_bf(f0.z); p0.w = f_to_bf(f0.w);
            p1.x = f_to_bf(f1.x); p1.y = f_to_bf(f1.y); p1.z = f_to_bf(f1.z); p1.w = f_to_bf(f1.w);
            p2.x = f_to_bf(f2.x); p2.y = f_to_bf(f2.y); p2.z = f_to_bf(f2.z); p2.w = f_to_bf(f2.w);
            p3.x = f_to_bf(f3.x); p3.y = f_to_bf(f3.y); p3.z = f_to_bf(f3.z); p3.w = f_to_bf(f3.w);
            *(ushort4*)&As[srow * LDA + skp + 0]  = p0;
            *(ushort4*)&As[srow * LDA + skp + 4]  = p1;
            *(ushort4*)&As[srow * LDA + skp + 8]  = p2;
            *(ushort4*)&As[srow * LDA + skp + 12] = p3;
        }
        {
            const uint4 b0 = *(const uint4*)(bsrc + kc);
            const uint4 b1 = *(const uint4*)(bsrc + kc + 8);
            *(uint4*)&Bs[srow * LDA + skp + 0] = b0;
            *(uint4*)&Bs[srow * LDA + skp + 8] = b1;
        }
        __syncthreads();

        bf16x8 af[4], bfr[4];
        #pragma unroll
        for (int mt = 0; mt < 4; ++mt)
            af[mt] = *(const bf16x8*)&As[(wm + mt * 16 + l15) * LDA + quad * 8];
        #pragma unroll
        for (int nt = 0; nt < 4; ++nt)
            bfr[nt] = *(const bf16x8*)&Bs[(wn + nt * 16 + l15) * LDA + quad * 8];
        #pragma unroll
        for (int mt = 0; mt < 4; ++mt)
            #pragma unroll
            for (int nt = 0; nt < 4; ++nt)
                acc[mt][nt] = __builtin_amdgcn_mfma_f32_16x16x32_bf16(
                    af[mt], bfr[nt], acc[mt][nt], 0, 0, 0);
        __syncthreads();
    }

    #pragma unroll
    for (int mt = 0; mt < 4; ++mt) {
        #pragma unroll
        for (int r = 0; r < 4; ++r) {
            const int grow = r0 + wm + mt * 16 + quad * 4 + r;
            if (grow < N_NODES) {
                u16* dst = Sb + (size_t)grow * OUT_DIM + n0 + wn + l15;
                #pragma unroll
                for (int nt = 0; nt < 4; ++nt)
                    dst[nt * 16] = f_to_bf(acc[mt][nt][r]);
            }
        }
    }
}

// ---------------------------------------------------------------------------
// out[r] = bias + sum_{e in row r} val[e] * Sb[col[e]]  (8-wide MLP batches)
// ---------------------------------------------------------------------------
__global__ __launch_bounds__(256) void csr_spmm(const int* __restrict__ row_ptr,
                                                const int2* __restrict__ sedge,
                                                const u16* __restrict__ Sb,
                                                const float* __restrict__ bias,
                                                float* __restrict__ out) {
    const int wave = threadIdx.x >> 6;
    const int lane = threadIdx.x & 63;
    const int r = blockIdx.x * 4 + wave;
    if (r >= N_NODES) return;

    const int start = row_ptr[r];
    const int end   = row_ptr[r + 1];

    float4 acc = *(const float4*)(bias + lane * 4);
    const u16* sbase = Sb + lane * 4;

    for (int e = start; e < end; e += 8) {
        int2 ed[8];
        #pragma unroll
        for (int j = 0; j < 8; ++j) {
            const int idx = min(e + j, end - 1);      // clamp: row nonempty here
            ed[j] = sedge[idx];
        }
        #pragma unroll
        for (int j = 0; j < 8; ++j)
            if (e + j >= end) ed[j].y = 0;            // 0.0f bits on padding

        ushort4 sv[8];
        #pragma unroll
        for (int j = 0; j < 8; ++j)
            sv[j] = *(const ushort4*)(sbase + (size_t)ed[j].x * OUT_DIM);

        #pragma unroll
        for (int j = 0; j < 8; ++j) {
            const float vj = __int_as_float(ed[j].y);
            acc.x += vj * bf_to_f(sv[j].x);
            acc.y += vj * bf_to_f(sv[j].y);
            acc.z += vj * bf_to_f(sv[j].z);
            acc.w += vj * bf_to_f(sv[j].w);
        }
    }

    *(float4*)(out + (size_t)r * OUT_DIM + lane * 4) = acc;
}

extern "C" void kernel_launch(void* const* d_in, const int* in_sizes, int n_in,
                              void* d_out, int out_size, void* d_ws, size_t ws_size,
                              hipStream_t stream) {
    const float* X    = (const float*)d_in[0];
    const int*   er   = (const int*)d_in[1];
    const int*   ec   = (const int*)d_in[2];
    const float* ev   = (const float*)d_in[3];
    const float* W    = (const float*)d_in[4];
    const float* bias = (const float*)d_in[5];
    float* out        = (float*)d_out;

    // ws layout (~38.9 MB).  tmp/cursor/bucket_base alias the Sb region:
    // they are dead before gemm_mfma writes Sb (stream-ordered).
    char* ws = (char*)d_ws;
    u16*  Sb      = (u16*) (ws);                       // 25,600,000 B
    int2* tmp     = (int2*)(ws);                       // 16,015,360 B (alias)
    int*  cursor  = (int*) (ws + 16100000);            //      1,564 B (alias)
    int*  bbase   = (int*) (ws + 16110000);            //      1,564 B (alias)
    int2* sedge   = (int2*)(ws + 25600000);            // 12,800,000 B
    u16*  WT      = (u16*) (ws + 38400000);            //    262,144 B
    int*  row_ptr = (int*) (ws + 38662144);            //    200,004 B

    hipLaunchKernelGGL(zero_cur, dim3(2), dim3(256), 0, stream, cursor);
    hipLaunchKernelGGL(scatter1, dim3((N_EDGES + CHUNK - 1) / CHUNK), dim3(256), 0,
                       stream, er, ec, ev, cursor, tmp);
    hipLaunchKernelGGL(bscan, dim3(1), dim3(256), 0, stream, cursor, bbase, row_ptr);
    hipLaunchKernelGGL(scatter2, dim3(NBKT), dim3(256), 0, stream,
                       cursor, bbase, tmp, row_ptr, sedge);
    hipLaunchKernelGGL(wcvt, dim3(IN_DIM / 4), dim3(256), 0, stream, W, WT);
    hipLaunchKernelGGL(gemm_mfma, dim3((N_NODES + BM - 1) / BM, OUT_DIM / BN),
                       dim3(256), 0, stream, X, WT, Sb);
    hipLaunchKernelGGL(csr_spmm, dim3((N_NODES + 3) / 4), dim3(256), 0, stream,
                       row_ptr, sedge, Sb, bias, out);
}